// Round 3
// baseline (351.534 us; speedup 1.0000x reference)
//
#include <hip/hip_runtime.h>
#include <math.h>

// B=2, H=16, S=4096, D=64, W=256. Output (2,4096,16,513) fp32.
// Fused: reads fp32 x directly (natural [b][h][s][d] layout), converts to
// bf16 hi/lo on the fly. No workspace, no split kernel.
#define S_LEN 4096
#define NHEAD 16
#define NC    513
#define TI    64          // query rows per block
#define CK    96          // key rows per LDS chunk (fp32)
#define NCH   6           // 6*96 = 576 = TI + 2*256 staged span
#define PV    (S_LEN * 64)

typedef __attribute__((ext_vector_type(8))) short short8;   // 8 bf16
typedef __attribute__((ext_vector_type(4))) float floatx4;  // MFMA C/D
typedef float float4u __attribute__((ext_vector_type(4), aligned(4)));

static __device__ __forceinline__ unsigned short f2bf_rn(float f) {
  unsigned int u = __float_as_uint(f);
  u += 0x7FFFu + ((u >> 16) & 1u);
  return (unsigned short)(u >> 16);
}

// 8 fp32 -> bf16 hi (trunc) + bf16 lo (rn of residual)
#define CVT1(F, i)                                                      \
  { const unsigned int u_ = __float_as_uint(F);                         \
    hh[i] = (short)(u_ >> 16);                                          \
    const float d_ = (F) - __uint_as_float(u_ & 0xFFFF0000u);           \
    ll[i] = (short)f2bf_rn(d_); }

static __device__ __forceinline__ void cv8(const float4 f0, const float4 f1,
                                           short8* h, short8* l) {
  short8 hh, ll;
  CVT1(f0.x, 0) CVT1(f0.y, 1) CVT1(f0.z, 2) CVT1(f0.w, 3)
  CVT1(f1.x, 4) CVT1(f1.y, 5) CVT1(f1.z, 6) CVT1(f1.w, 7)
  *h = hh; *l = ll;
}

// Swapped-operand MFMA: D[key = quad*4+reg][q = lane&15]. Wave w owns key
// tiles g == w (mod 4) x ALL 4 q-groups -> each K-frag read feeds 12 MFMAs.
__global__ __launch_bounds__(256, 2)
void attn_kernel(const float* __restrict__ x, float* __restrict__ out) {
  const int t  = threadIdx.x;
  const int id = blockIdx.x;
  // XCD swizzle: id%8 == c handles tiles [8c, 8c+8) of each p
  const int p    = id >> 6;
  const int r6   = id & 63;
  const int tile = ((r6 & 7) << 3) | (r6 >> 3);
  const int i0   = tile * TI;
  const int b    = p >> 4;
  const int hh_  = p & 15;
  const int jb   = i0 - 256;          // staged key span [jb, jb+576)
  const int w    = t >> 6;
  const int quad = (t >> 4) & 3;
  const int n    = t & 15;

  __shared__ float Kb[2][CK * 64];    // fp32 chunks, 16B-granule XOR swizzled
  __shared__ float red[2][4][TI];     // [max|sum][wave][row]

  const float* xs = x + (size_t)p * PV;

  // STAGE chunk mm into Kb[buf]: linear LDS dest (global_load_lds rule),
  // source granule pre-swizzled: col16_src = g16 ^ (row & 15).
#define STAGE(mm, buf)                                                  \
  { _Pragma("unroll")                                                   \
    for (int r = 0; r < 6; ++r) {                                       \
      const int a   = r * 4096 + t * 16;    /* lds byte offset */       \
      const int row = a >> 8;                                           \
      const int g16 = (a >> 4) & 15;                                    \
      int v = jb + (mm) * CK + row;                                     \
      v = v < 0 ? 0 : (v > 4095 ? 4095 : v); /* clamp: garbage is masked */ \
      const float* src = xs + (size_t)v * 64 + ((g16 ^ (row & 15)) << 2); \
      float* dst = (float*)Kb[buf] + ((r * 4096 + (t & 192) * 16) >> 2); \
      __builtin_amdgcn_global_load_lds(                                 \
          (const __attribute__((address_space(1))) void*)src,           \
          (__attribute__((address_space(3))) void*)dst, 16, 0, 0);      \
    } }

  STAGE(0, 0)

  // ---- Q fragments straight from global, convert in-register ----
  // B-operand layout: B[k = quad*8 + j][q = lane&15]; halves k<32, k>=32.
  short8 qh[4][2], ql[4][2];
#pragma unroll
  for (int gq = 0; gq < 4; ++gq) {
    const float* qr = xs + (size_t)(i0 + 16 * gq + n) * 64;
#pragma unroll
    for (int h2 = 0; h2 < 2; ++h2) {
      const float4 f0 = *(const float4*)(qr + h2 * 32 + quad * 8);
      const float4 f1 = *(const float4*)(qr + h2 * 32 + quad * 8 + 4);
      cv8(f0, f1, &qh[gq][h2], &ql[gq][h2]);
    }
  }

  floatx4 acc[4][9];
#pragma unroll
  for (int gq = 0; gq < 4; ++gq)
#pragma unroll
    for (int jt = 0; jt < 9; ++jt) acc[gq][jt] = (floatx4){0.f, 0.f, 0.f, 0.f};

  asm volatile("s_waitcnt vmcnt(0)" ::: "memory");
  __builtin_amdgcn_s_barrier();
  __builtin_amdgcn_sched_barrier(0);

  // ---- main loop: 2-phase (issue next chunk, compute current) ----
#pragma unroll
  for (int m = 0; m < NCH; ++m) {
    if (m < NCH - 1) STAGE(m + 1, (m + 1) & 1)
    const float* kb = (const float*)Kb[m & 1];
#pragma unroll
    for (int u6 = 0; u6 < 6; ++u6) {
      const int g = m * 6 + u6;                       // global key tile 0..35
      if ((g & 3) != w) continue;                     // ownership (uniform)
      if (jb + 16 * g > 4095 || jb + 16 * g + 15 < 0) continue;  // all-OOB
      const int kr = (u6 << 4) + n;                   // row in chunk
      const int sw = kr & 15;
      const float* rp = kb + kr * 64;
#pragma unroll
      for (int h2 = 0; h2 < 2; ++h2) {
        const float4 a0 = *(const float4*)(rp + (((8 * h2 + 2 * quad + 0) ^ sw) << 2));
        const float4 a1 = *(const float4*)(rp + (((8 * h2 + 2 * quad + 1) ^ sw) << 2));
        short8 bh, bl;
        cv8(a0, a1, &bh, &bl);
#pragma unroll
        for (int gq = 0; gq < 4; ++gq) {
          if (g - gq < 0 || g - gq > 32) continue;    // compile-time dead pair
          floatx4 c = acc[gq][g >> 2];
          c = __builtin_amdgcn_mfma_f32_16x16x32_bf16(bh, ql[gq][h2], c, 0, 0, 0);
          c = __builtin_amdgcn_mfma_f32_16x16x32_bf16(bl, qh[gq][h2], c, 0, 0, 0);
          c = __builtin_amdgcn_mfma_f32_16x16x32_bf16(bh, qh[gq][h2], c, 0, 0, 0);
          acc[gq][g >> 2] = c;
        }
      }
    }
    asm volatile("s_waitcnt vmcnt(0)" ::: "memory");  // next chunk landed
    __builtin_amdgcn_s_barrier();                     // all done reading cur
    __builtin_amdgcn_sched_barrier(0);
  }

  // ---- epilogue: in-lane softmax, cross-quad shfl, cross-wave LDS ----
  // Per lane, gq: c = 16g + cb + reg, j = jb + 16g + 4quad + reg.
  float mxr[4], smr[4];
#pragma unroll
  for (int gq = 0; gq < 4; ++gq) {
    float mx = acc[gq][0][0];
#pragma unroll
    for (int jt = 0; jt < 9; ++jt)
#pragma unroll
      for (int rg = 0; rg < 4; ++rg) mx = fmaxf(mx, acc[gq][jt][rg]);
    mx = fmaxf(mx, __shfl_xor(mx, 16, 64));
    mx = fmaxf(mx, __shfl_xor(mx, 32, 64));
    if (quad == 0) red[0][w][16 * gq + n] = mx;
  }
  __syncthreads();
#pragma unroll
  for (int gq = 0; gq < 4; ++gq)
    mxr[gq] = fmaxf(fmaxf(red[0][0][16 * gq + n], red[0][1][16 * gq + n]),
                    fmaxf(red[0][2][16 * gq + n], red[0][3][16 * gq + n]));

#pragma unroll
  for (int gq = 0; gq < 4; ++gq) {
    const int cb = 4 * quad - 16 * gq - n;
    float sm = 0.f;
#pragma unroll
    for (int jt = 0; jt < 9; ++jt) {
      const int g  = 4 * jt + w;
      const int c0 = 16 * g + cb;
      const int j0 = jb + 16 * g + 4 * quad;
#pragma unroll
      for (int rg = 0; rg < 4; ++rg) {
        float e = __expf(acc[gq][jt][rg] - mxr[gq]);  // <= 1: mx is global max
        const bool ok = ((unsigned)(c0 + rg) <= 512u) &
                        ((unsigned)(j0 + rg) < (unsigned)S_LEN);
        e = ok ? e : 0.f;
        acc[gq][jt][rg] = e;
        sm += e;
      }
    }
    sm += __shfl_xor(sm, 16, 64);
    sm += __shfl_xor(sm, 32, 64);
    if (quad == 0) red[1][w][16 * gq + n] = sm;
  }
  __syncthreads();
#pragma unroll
  for (int gq = 0; gq < 4; ++gq)
    smr[gq] = red[1][0][16 * gq + n] + red[1][1][16 * gq + n] +
              red[1][2][16 * gq + n] + red[1][3][16 * gq + n];

#pragma unroll
  for (int gq = 0; gq < 4; ++gq) {
    const float inv = 1.0f / smr[gq];   // diagonal always in-band -> sm > 0
    const int i = i0 + 16 * gq + n;
    float* pr = out + (((size_t)(b * S_LEN + i) * NHEAD) + hh_) * NC;
    const int cb = 4 * quad - 16 * gq - n;
#pragma unroll
    for (int jt = 0; jt < 9; ++jt) {
      const int g  = 4 * jt + w;
      const int j0 = jb + 16 * g + 4 * quad;
      if ((unsigned)j0 > 4092u) continue;     // j0 % 4 == 0 -> all-or-nothing
      const int c0 = 16 * g + cb;
      if (c0 >= 0 && c0 <= 509) {
        float4u v = {acc[gq][jt][0] * inv, acc[gq][jt][1] * inv,
                     acc[gq][jt][2] * inv, acc[gq][jt][3] * inv};
        *(float4u*)(pr + c0) = v;
      } else if (c0 > -4 && c0 < 513) {       // band-edge partial
#pragma unroll
        for (int rg = 0; rg < 4; ++rg) {
          const int cc = c0 + rg;
          if ((unsigned)cc <= 512u) pr[cc] = acc[gq][jt][rg] * inv;
        }
      }
    }
  }
#undef STAGE
}

extern "C" void kernel_launch(void* const* d_in, const int* in_sizes, int n_in,
                              void* d_out, int out_size, void* d_ws, size_t ws_size,
                              hipStream_t stream) {
  const float* x = (const float*)d_in[0];
  float* out = (float*)d_out;
  attn_kernel<<<32 * 64, 256, 0, stream>>>(x, out);
}